// Round 14
// baseline (59.224 us; speedup 1.0000x reference)
//
#include <hip/hip_runtime.h>
#include <cstdint>

#define BB 8
#define NN 2048
#define CC 64
#define TI 128           // i-rows per block (8 waves x 16)
#define JSPLIT 2
#define KRANGE (NN / JSPLIT)   // 1024 j per block
#define NCH 8                  // mask words per thread (4 K-steps each)

typedef __attribute__((ext_vector_type(8))) _Float16 f16x8;
typedef __attribute__((ext_vector_type(4))) float f32x4;
typedef __attribute__((ext_vector_type(4))) unsigned int u32x4;
typedef __attribute__((ext_vector_type(4))) int i32x4;

// ws layout (in floats):
static const size_t WS_H   = 0;                                  // B*N*C
static const size_t WS_E1  = WS_H  + (size_t)BB*NN*CC;           // B*N
static const size_t WS_E2  = WS_E1 + (size_t)BB*NN;              // B*N
static const size_t WS_HT  = WS_E2 + (size_t)BB*NN;              // hT fp16: B*C*N ushorts
static const size_t WS_ACC = WS_HT + (size_t)BB*CC*NN/2;         // JSPLIT*B*N*C floats
static const size_t WS_Z   = WS_ACC + (size_t)JSPLIT*BB*NN*CC;   // JSPLIT*B*N
static const size_t WS_MSK = WS_Z   + (size_t)JSPLIT*BB*NN;      // 4 MB mask (1M floats)

#define GL16(g, l) __builtin_amdgcn_global_load_lds( \
    (const __attribute__((address_space(1))) void*)(g), \
    (__attribute__((address_space(3))) void*)(uint32_t)(uintptr_t)(l), 16, 0, 0)
#define GL4(g, l) __builtin_amdgcn_global_load_lds( \
    (const __attribute__((address_space(1))) void*)(g), \
    (__attribute__((address_space(3))) void*)(uint32_t)(uintptr_t)(l), 4, 0, 0)
#define WAIT0()  asm volatile("s_waitcnt vmcnt(0)" ::: "memory")
#define BAR()    __builtin_amdgcn_s_barrier()

// ---------------- Kernel 0: pack adj (128 MB) -> bitmask (4 MB), k2-native layout ----------------
// mask[b][kg][row][gstep]: byte = bits j = gstep*32 + kg*8 + 0..7 of adj[b][row][.]
// Pure streaming kernel: one wave per row per iteration; lane l = gstep l (32 ints, 8x int4).
__global__ __launch_bounds__(256) void kpack(const int* __restrict__ adj,
        unsigned char* __restrict__ mask) {
    int bid = blockIdx.x;
    int b = bid & 7;
    int rowgrp = bid >> 3;            // 0..511
    int w = threadIdx.x >> 6;
    int l = threadIdx.x & 63;
    int row = rowgrp * 4 + w;
    const int* ar = adj + ((size_t)b * NN + row) * NN + l * 32;
    i32x4 a[8];
    #pragma unroll
    for (int q = 0; q < 8; q++) a[q] = ((const i32x4*)ar)[q];
    #pragma unroll
    for (int kg = 0; kg < 4; kg++) {
        unsigned int byte = 0;
        #pragma unroll
        for (int i = 0; i < 4; i++) {
            byte |= (a[2 * kg][i]     > 0 ? 1u : 0u) << i;
            byte |= (a[2 * kg + 1][i] > 0 ? 1u : 0u) << (i + 4);
        }
        mask[(((size_t)b * 4 + kg) * NN + row) * 64 + l] = (unsigned char)byte;
    }
}

// ---------------- Kernel 1: h = inp @ W ; e1 = h@a1 ; e2 = h@a2 (proven) ----------------
__global__ __launch_bounds__(256) void k1_proj(const float* __restrict__ inp,
        const float* __restrict__ Wm, const float* __restrict__ av,
        float* __restrict__ h, float* __restrict__ e1, float* __restrict__ e2) {
    __shared__ float inp_lds[256];
    int t = threadIdx.x;
    size_t base = (size_t)blockIdx.x * 256;
    inp_lds[t] = inp[base + t];
    __syncthreads();
    int r = t >> 6;
    int c = t & 63;
    const float* irow = &inp_lds[r * 64];
    float acc = 0.f;
    #pragma unroll
    for (int k = 0; k < 64; k++) acc = fmaf(irow[k], Wm[k * 64 + c], acc);
    size_t row = (size_t)blockIdx.x * 4 + r;
    h[row * 64 + c] = acc;
    float v1 = acc * av[c];
    float v2 = acc * av[64 + c];
    #pragma unroll
    for (int o = 32; o > 0; o >>= 1) {
        v1 += __shfl_down(v1, o);
        v2 += __shfl_down(v2, o);
    }
    if (c == 0) { e1[row] = v1; e2[row] = v2; }
}

// ---------------- Kernel 1b: transpose h -> fp16 [b][c][n]; XCD-affine (b=bid&7) ----------------
__global__ __launch_bounds__(256) void k1b_transpose(const float* __restrict__ h,
        unsigned short* __restrict__ hT) {
    __shared__ float tile[64][65];
    int t = threadIdx.x;
    int b = blockIdx.x & 7;
    int i0 = ((blockIdx.x >> 3) & 31) * 64;
    const float* hb = h + ((size_t)b * NN + i0) * CC;
    #pragma unroll
    for (int q = 0; q < 16; q++) {
        int idx = q * 256 + t;
        tile[idx >> 6][idx & 63] = hb[idx];
    }
    __syncthreads();
    int c = t & 63;
    int rgrp = t >> 6;           // 4 groups of 16 rows
    unsigned int uh[8];
    #pragma unroll
    for (int p = 0; p < 8; p++) {
        unsigned int pack_h = 0;
        #pragma unroll
        for (int s = 0; s < 2; s++) {
            float v = tile[rgrp * 16 + p * 2 + s][c];
            _Float16 fh = (_Float16)v;
            unsigned int u = (unsigned int)__builtin_bit_cast(unsigned short, fh);
            pack_h |= u << (16 * s);
        }
        uh[p] = pack_h;
    }
    size_t off = ((size_t)b * 64 + c) * NN + i0 + rgrp * 16;   // in ushorts
    u32x4* dh = (u32x4*)(hT + off);
    dh[0] = u32x4{uh[0], uh[1], uh[2], uh[3]};
    dh[1] = u32x4{uh[4], uh[5], uh[6], uh[7]};
}

// ---------------- Kernel 2: fp16 MFMA attention; h-half LDS-resident; mask-driven ----------------
// grid 256 @ 512 thr: b = bid&7 (XCD<->batch affinity). h-half (128 KB) + e2 (4 KB) staged
// once; per-thread 32 B mask load replaces the adj stream; main loop has ZERO global loads.
__global__ __launch_bounds__(512, 1) void k2_mfma(const unsigned char* __restrict__ mask,
        const unsigned short* __restrict__ hT,
        const float* __restrict__ e1, const float* __restrict__ e2,
        float* __restrict__ accp, float* __restrict__ zp) {
    __shared__ __align__(16) char smem[135168];   // 128 KB h + 4 KB e2
    float* e2L = (float*)(smem + 131072);

    int bid = blockIdx.x;
    int b    = bid & 7;
    int rest = bid >> 3;
    int s    = rest & 1;
    int tile = rest >> 1;          // 0..15
    int i0 = tile * TI;
    int jbase = s * KRANGE;

    int t = threadIdx.x;
    int w = t >> 6;
    int l = t & 63;
    int col = l & 15;
    int kg  = l >> 4;              // k-group 0..3

    int myrow = i0 + w * 16 + col;
    float e1v = e1[(size_t)b * NN + myrow];
    const float* e2b = e2 + (size_t)b * NN;
    const unsigned short* hTb = hT + (size_t)b * 64 * NN;

    // ---- per-thread mask: 32 bytes = 32 K-steps (this kg-slice of rows' j-range) ----
    const unsigned char* mrow = mask + (((size_t)b * 4 + kg) * NN + myrow) * 64 + s * 32;
    u32x4 m0 = *(const u32x4*)(mrow);
    u32x4 m1 = *(const u32x4*)(mrow + 16);
    unsigned int mm[8] = {m0.x, m0.y, m0.z, m0.w, m1.x, m1.y, m1.z, m1.w};

    f32x4 acc[4];
    #pragma unroll
    for (int n = 0; n < 4; n++) acc[n] = f32x4{0.f, 0.f, 0.f, 0.f};
    f32x4 accZ = f32x4{0.f, 0.f, 0.f, 0.f};

    _Float16 onev = (_Float16)1.0f, zerov = (_Float16)0.0f;
    f16x8 onesf;
    #pragma unroll
    for (int i = 0; i < 8; i++) onesf[i] = (col == 0) ? onev : zerov;

    // ---- stage h-half (128 KB) once: 16 GL16 per wave, swizzled global source ----
    #pragma unroll
    for (int it = 0; it < 16; it++) {
        int k16 = it * 8 + w;            // half-row index 0..127 (wave-uniform)
        int c   = k16 >> 1;              // LDS row
        int p   = (k16 & 1) * 64 + l;    // physical granule within row
        int g   = (p & 120) | ((p ^ c) & 7);   // logical granule (involution)
        const unsigned short* src = hTb + (size_t)c * NN + jbase + g * 8;
        GL16(src, smem + (size_t)k16 * 1024);
    }
    // ---- stage e2 half-slice (4 KB) once ----
    #pragma unroll
    for (int it = 0; it < 2; it++) {
        GL4(e2b + jbase + it * 512 + w * 64 + l,
            smem + 131072 + (it * 512 + w * 64) * 4);
    }
    WAIT0();
    BAR();

#define COMPUTE(jcN) { \
    unsigned int mword = mm[jcN]; \
    _Pragma("unroll") \
    for (int ks4 = 0; ks4 < 4; ks4++) { \
        int ks = (jcN) * 4 + ks4; \
        int krel = ks * 32 + kg * 8; \
        unsigned int mbyte = (mword >> (ks4 * 8)) & 0xffu; \
        f32x4 e20 = *(const f32x4*)(e2L + krel); \
        f32x4 e21 = *(const f32x4*)(e2L + krel + 4); \
        float xs[8] = {e20.x, e20.y, e20.z, e20.w, e21.x, e21.y, e21.z, e21.w}; \
        f16x8 pf; \
        _Pragma("unroll") \
        for (int i = 0; i < 8; i++) { \
            float x = e1v + xs[i]; \
            x = fmaxf(x, 0.01f * x); \
            x = __expf(x); \
            x = ((mbyte >> i) & 1u) ? x : 0.0f; \
            pf[i] = (_Float16)x; \
        } \
        int g = ks * 4 + kg; \
        _Pragma("unroll") \
        for (int n = 0; n < 4; n++) { \
            int c = n * 16 + col; \
            int p = (g & 120) | ((g ^ c) & 7); \
            f16x8 hv = __builtin_bit_cast(f16x8, *(const f32x4*)(smem + c * 2048 + p * 16)); \
            acc[n] = __builtin_amdgcn_mfma_f32_16x16x32_f16(pf, hv, acc[n], 0, 0, 0); \
        } \
        accZ = __builtin_amdgcn_mfma_f32_16x16x32_f16(pf, onesf, accZ, 0, 0, 0); \
    } \
}

    // ---- main loop: zero global loads ----
    #pragma unroll
    for (int jc = 0; jc < NCH; jc++) COMPUTE(jc);

    // ---- epilogue: partial acc/Z to ws (C/D layout: col=lane&15, row=kg*4+reg) ----
    size_t orow = (size_t)s * BB * NN + (size_t)b * NN + i0 + w * 16 + kg * 4;
    float* accout = accp + orow * CC;
    #pragma unroll
    for (int n = 0; n < 4; n++) {
        #pragma unroll
        for (int r = 0; r < 4; r++) {
            accout[(size_t)r * CC + n * 16 + col] = acc[n][r];
        }
    }
    if (col == 0) {
        #pragma unroll
        for (int r = 0; r < 4; r++) zp[orow + r] = accZ[r];
    }
#undef COMPUTE
}

// ---------------- Kernel 3: out = sum_s acc[s] / sum_s z[s] ----------------
__global__ __launch_bounds__(256) void k3_final(const float* __restrict__ accp,
        const float* __restrict__ zp, float* __restrict__ out) {
    int idx = blockIdx.x * 256 + threadIdx.x;      // float4 index
    const int TOT4 = BB * NN * CC / 4;             // 262144
    if (idx >= TOT4) return;
    int row = idx >> 4;
    f32x4 s0 = ((const f32x4*)accp)[idx];
    f32x4 s1 = ((const f32x4*)accp)[idx + TOT4];
    float z = zp[row] + zp[row + BB * NN];
    float inv = (z > 0.f) ? (1.0f / z) : 0.f;
    f32x4 o;
    o.x = (s0.x + s1.x) * inv;
    o.y = (s0.y + s1.y) * inv;
    o.z = (s0.z + s1.z) * inv;
    o.w = (s0.w + s1.w) * inv;
    ((f32x4*)out)[idx] = o;
}

extern "C" void kernel_launch(void* const* d_in, const int* in_sizes, int n_in,
                              void* d_out, int out_size, void* d_ws, size_t ws_size,
                              hipStream_t stream) {
    const float* inp = (const float*)d_in[0];
    const int*   adj = (const int*)d_in[1];
    const float* Wm  = (const float*)d_in[2];
    const float* av  = (const float*)d_in[3];
    float* ws = (float*)d_ws;
    float* h    = ws + WS_H;
    float* e1   = ws + WS_E1;
    float* e2   = ws + WS_E2;
    unsigned short* hT = (unsigned short*)(ws + WS_HT);
    float* accp = ws + WS_ACC;
    float* zp   = ws + WS_Z;
    unsigned char* mask = (unsigned char*)(ws + WS_MSK);
    float* out  = (float*)d_out;

    kpack<<<BB * (NN / 4), 256, 0, stream>>>(adj, mask);
    k1_proj<<<BB * NN / 4, 256, 0, stream>>>(inp, Wm, av, h, e1, e2);
    k1b_transpose<<<BB * (NN / 64), 256, 0, stream>>>(h, hT);
    k2_mfma<<<BB * (NN / TI) * JSPLIT, 512, 0, stream>>>(mask, hT, e1, e2, accp, zp);
    k3_final<<<(BB * NN * CC / 4 + 255) / 256, 256, 0, stream>>>(accp, zp, out);
}

// Round 15
// 46.243 us; speedup vs baseline: 1.2807x; 1.2807x over previous
//
#include <hip/hip_runtime.h>
#include <cstdint>

#define BB 8
#define NN 2048
#define CC 64
#define TI 128           // i-rows per block (8 waves x 16)
#define JSPLIT 2
#define KRANGE (NN / JSPLIT)   // 1024 j per block
#define JCH 128                // adj reg-prefetch chunk
#define NCH (KRANGE / JCH)     // 8

typedef __attribute__((ext_vector_type(8))) _Float16 f16x8;
typedef __attribute__((ext_vector_type(4))) float f32x4;
typedef __attribute__((ext_vector_type(4))) unsigned int u32x4;
typedef __attribute__((ext_vector_type(4))) int i32x4;

// ws layout (in floats):
static const size_t WS_H   = 0;                                  // B*N*C
static const size_t WS_E1  = WS_H  + (size_t)BB*NN*CC;           // B*N
static const size_t WS_B   = WS_E1 + (size_t)BB*NN;              // B*N  exp(e2)
static const size_t WS_BS  = WS_B  + (size_t)BB*NN;              // B*N  exp(0.01*e2)
static const size_t WS_HT  = WS_BS + (size_t)BB*NN;              // hT fp16: B*C*N ushorts
static const size_t WS_ACC = WS_HT + (size_t)BB*CC*NN/2;         // JSPLIT*B*N*C floats
static const size_t WS_Z   = WS_ACC + (size_t)JSPLIT*BB*NN*CC;   // JSPLIT*B*N

#define GL16(g, l) __builtin_amdgcn_global_load_lds( \
    (const __attribute__((address_space(1))) void*)(g), \
    (__attribute__((address_space(3))) void*)(uint32_t)(uintptr_t)(l), 16, 0, 0)
#define GL4(g, l) __builtin_amdgcn_global_load_lds( \
    (const __attribute__((address_space(1))) void*)(g), \
    (__attribute__((address_space(3))) void*)(uint32_t)(uintptr_t)(l), 4, 0, 0)
#define WAIT0()  asm volatile("s_waitcnt vmcnt(0)" ::: "memory")
#define BAR()    __builtin_amdgcn_s_barrier()

// ---------------- Kernel 1: h = inp @ W ; e1 ; B=exp(e2), b=exp(0.01 e2) ----------------
__global__ __launch_bounds__(256) void k1_proj(const float* __restrict__ inp,
        const float* __restrict__ Wm, const float* __restrict__ av,
        float* __restrict__ h, float* __restrict__ e1,
        float* __restrict__ Bv, float* __restrict__ bv) {
    __shared__ float inp_lds[256];
    int t = threadIdx.x;
    size_t base = (size_t)blockIdx.x * 256;
    inp_lds[t] = inp[base + t];
    __syncthreads();
    int r = t >> 6;
    int c = t & 63;
    const float* irow = &inp_lds[r * 64];
    float acc = 0.f;
    #pragma unroll
    for (int k = 0; k < 64; k++) acc = fmaf(irow[k], Wm[k * 64 + c], acc);
    size_t row = (size_t)blockIdx.x * 4 + r;
    h[row * 64 + c] = acc;
    float v1 = acc * av[c];
    float v2 = acc * av[64 + c];
    #pragma unroll
    for (int o = 32; o > 0; o >>= 1) {
        v1 += __shfl_down(v1, o);
        v2 += __shfl_down(v2, o);
    }
    if (c == 0) {
        e1[row] = v1;
        Bv[row] = __expf(v2);
        bv[row] = __expf(0.01f * v2);
    }
}

// ---------------- Kernel 1b: transpose h -> fp16 [b][c][n]; XCD-affine (b=bid&7) ----------------
__global__ __launch_bounds__(256) void k1b_transpose(const float* __restrict__ h,
        unsigned short* __restrict__ hT) {
    __shared__ float tile[64][65];
    int t = threadIdx.x;
    int b = blockIdx.x & 7;
    int i0 = ((blockIdx.x >> 3) & 31) * 64;
    const float* hb = h + ((size_t)b * NN + i0) * CC;
    #pragma unroll
    for (int q = 0; q < 16; q++) {
        int idx = q * 256 + t;
        tile[idx >> 6][idx & 63] = hb[idx];
    }
    __syncthreads();
    int c = t & 63;
    int rgrp = t >> 6;           // 4 groups of 16 rows
    unsigned int uh[8];
    #pragma unroll
    for (int p = 0; p < 8; p++) {
        unsigned int pack_h = 0;
        #pragma unroll
        for (int s = 0; s < 2; s++) {
            float v = tile[rgrp * 16 + p * 2 + s][c];
            _Float16 fh = (_Float16)v;
            unsigned int u = (unsigned int)__builtin_bit_cast(unsigned short, fh);
            pack_h |= u << (16 * s);
        }
        uh[p] = pack_h;
    }
    size_t off = ((size_t)b * 64 + c) * NN + i0 + rgrp * 16;   // in ushorts
    u32x4* dh = (u32x4*)(hT + off);
    dh[0] = u32x4{uh[0], uh[1], uh[2], uh[3]};
    dh[1] = u32x4{uh[4], uh[5], uh[6], uh[7]};
}

// ---------------- Kernel 2: fp16 MFMA attention; h-half LDS-resident; exp-free inner loop ----------------
// grid 256 @ 512 thr: b = bid&7 (XCD<->batch affinity). Structure = round-10 (best).
// Inner element: p = adj ? max(A*B[j], a*b[j]) : 0  — exact identity for exp(leaky(e1+e2)),
// ZERO transcendentals in the loop (256 -> 2 exp per thread; v_exp is quarter-rate).
__global__ __launch_bounds__(512, 1) void k2_mfma(const int* __restrict__ adj,
        const unsigned short* __restrict__ hT,
        const float* __restrict__ e1, const float* __restrict__ Bg,
        const float* __restrict__ bg,
        float* __restrict__ accp, float* __restrict__ zp) {
    __shared__ __align__(16) char smem[139264];   // 128 KB h + 4 KB B + 4 KB b
    float* BL = (float*)(smem + 131072);
    float* bL = (float*)(smem + 135168);

    int bid = blockIdx.x;
    int b    = bid & 7;
    int rest = bid >> 3;
    int s    = rest & 1;
    int tile = rest >> 1;          // 0..15
    int i0 = tile * TI;
    int jbase = s * KRANGE;

    int t = threadIdx.x;
    int w = t >> 6;
    int l = t & 63;
    int col = l & 15;
    int kg  = l >> 4;              // k-group 0..3

    const int* adjrow = adj + ((size_t)b * NN + i0 + w * 16 + col) * NN + jbase;
    float e1v = e1[(size_t)b * NN + i0 + w * 16 + col];
    float Arow = __expf(e1v);
    float arow = __expf(0.01f * e1v);
    const float* Bb = Bg + (size_t)b * NN;
    const float* bb = bg + (size_t)b * NN;
    const unsigned short* hTb = hT + (size_t)b * 64 * NN;

    f32x4 acc[4];
    #pragma unroll
    for (int n = 0; n < 4; n++) acc[n] = f32x4{0.f, 0.f, 0.f, 0.f};
    f32x4 accZ = f32x4{0.f, 0.f, 0.f, 0.f};

    _Float16 onev = (_Float16)1.0f, zerov = (_Float16)0.0f;
    f16x8 onesf;
    #pragma unroll
    for (int i = 0; i < 8; i++) onesf[i] = (col == 0) ? onev : zerov;

    i32x4 aA[8], aB[8];

#define ADJP(jcN, arr) { \
    _Pragma("unroll") \
    for (int q = 0; q < 4; q++) { \
        const i32x4* ap = (const i32x4*)(adjrow + (jcN) * JCH + q * 32 + kg * 8); \
        arr[2 * q]     = ap[0]; \
        arr[2 * q + 1] = ap[1]; \
    } \
}

#define COMPUTE(jcN, arr) { \
    _Pragma("unroll") \
    for (int ks4 = 0; ks4 < 4; ks4++) { \
        int ks = (jcN) * 4 + ks4; \
        int krel = ks * 32 + kg * 8; \
        i32x4 a0 = arr[2 * ks4]; \
        i32x4 a1 = arr[2 * ks4 + 1]; \
        f32x4 B0 = *(const f32x4*)(BL + krel); \
        f32x4 B1 = *(const f32x4*)(BL + krel + 4); \
        f32x4 b0 = *(const f32x4*)(bL + krel); \
        f32x4 b1 = *(const f32x4*)(bL + krel + 4); \
        float Bs[8] = {B0.x, B0.y, B0.z, B0.w, B1.x, B1.y, B1.z, B1.w}; \
        float bs[8] = {b0.x, b0.y, b0.z, b0.w, b1.x, b1.y, b1.z, b1.w}; \
        int ms[8] = {a0.x, a0.y, a0.z, a0.w, a1.x, a1.y, a1.z, a1.w}; \
        f16x8 pf; \
        _Pragma("unroll") \
        for (int i = 0; i < 8; i++) { \
            float x = fmaxf(Arow * Bs[i], arow * bs[i]); \
            x = (ms[i] > 0) ? x : 0.0f; \
            pf[i] = (_Float16)x; \
        } \
        int g = ks * 4 + kg; \
        _Pragma("unroll") \
        for (int n = 0; n < 4; n++) { \
            int c = n * 16 + col; \
            int p = (g & 120) | ((g ^ c) & 7); \
            f16x8 hv = __builtin_bit_cast(f16x8, *(const f32x4*)(smem + c * 2048 + p * 16)); \
            acc[n] = __builtin_amdgcn_mfma_f32_16x16x32_f16(pf, hv, acc[n], 0, 0, 0); \
        } \
        accZ = __builtin_amdgcn_mfma_f32_16x16x32_f16(pf, onesf, accZ, 0, 0, 0); \
    } \
}

    // ---- adj chunk 0 prefetch first: latency overlaps the h staging ----
    ADJP(0, aA);

    // ---- stage h-half (128 KB) once: 16 GL16 per wave, swizzled global source ----
    #pragma unroll
    for (int it = 0; it < 16; it++) {
        int k16 = it * 8 + w;            // half-row index 0..127 (wave-uniform)
        int c   = k16 >> 1;              // LDS row
        int p   = (k16 & 1) * 64 + l;    // physical granule within row
        int g   = (p & 120) | ((p ^ c) & 7);   // logical granule (involution)
        const unsigned short* src = hTb + (size_t)c * NN + jbase + g * 8;
        GL16(src, smem + (size_t)k16 * 1024);
    }
    // ---- stage B/b half-slices (4 KB each) once ----
    #pragma unroll
    for (int it = 0; it < 2; it++) {
        int idx = it * 512 + w * 64;
        GL4(Bb + jbase + idx + l, smem + 131072 + idx * 4);
        GL4(bb + jbase + idx + l, smem + 135168 + idx * 4);
    }
    WAIT0();
    BAR();

    // ---- barrier-free main loop, 2-deep rotation (round-10 proven pattern) ----
    #pragma unroll
    for (int jc = 0; jc < NCH; jc += 2) {
        ADJP(jc + 1, aB);
        COMPUTE(jc, aA);
        if (jc + 2 < NCH) ADJP(jc + 2, aA);
        COMPUTE(jc + 1, aB);
    }

    // ---- epilogue: partial acc/Z to ws (C/D layout: col=lane&15, row=kg*4+reg) ----
    size_t orow = (size_t)s * BB * NN + (size_t)b * NN + i0 + w * 16 + kg * 4;
    float* accout = accp + orow * CC;
    #pragma unroll
    for (int n = 0; n < 4; n++) {
        #pragma unroll
        for (int r = 0; r < 4; r++) {
            accout[(size_t)r * CC + n * 16 + col] = acc[n][r];
        }
    }
    if (col == 0) {
        #pragma unroll
        for (int r = 0; r < 4; r++) zp[orow + r] = accZ[r];
    }
#undef ADJP
#undef COMPUTE
}

// ---------------- Kernel 3: out = sum_s acc[s] / sum_s z[s] ----------------
__global__ __launch_bounds__(256) void k3_final(const float* __restrict__ accp,
        const float* __restrict__ zp, float* __restrict__ out) {
    int idx = blockIdx.x * 256 + threadIdx.x;      // float4 index
    const int TOT4 = BB * NN * CC / 4;             // 262144
    if (idx >= TOT4) return;
    int row = idx >> 4;
    f32x4 s0 = ((const f32x4*)accp)[idx];
    f32x4 s1 = ((const f32x4*)accp)[idx + TOT4];
    float z = zp[row] + zp[row + BB * NN];
    float inv = (z > 0.f) ? (1.0f / z) : 0.f;
    f32x4 o;
    o.x = (s0.x + s1.x) * inv;
    o.y = (s0.y + s1.y) * inv;
    o.z = (s0.z + s1.z) * inv;
    o.w = (s0.w + s1.w) * inv;
    ((f32x4*)out)[idx] = o;
}

extern "C" void kernel_launch(void* const* d_in, const int* in_sizes, int n_in,
                              void* d_out, int out_size, void* d_ws, size_t ws_size,
                              hipStream_t stream) {
    const float* inp = (const float*)d_in[0];
    const int*   adj = (const int*)d_in[1];
    const float* Wm  = (const float*)d_in[2];
    const float* av  = (const float*)d_in[3];
    float* ws = (float*)d_ws;
    float* h    = ws + WS_H;
    float* e1   = ws + WS_E1;
    float* Bv   = ws + WS_B;
    float* bv   = ws + WS_BS;
    unsigned short* hT = (unsigned short*)(ws + WS_HT);
    float* accp = ws + WS_ACC;
    float* zp   = ws + WS_Z;
    float* out  = (float*)d_out;

    k1_proj<<<BB * NN / 4, 256, 0, stream>>>(inp, Wm, av, h, e1, Bv, bv);
    k1b_transpose<<<BB * (NN / 64), 256, 0, stream>>>(h, hT);
    k2_mfma<<<BB * (NN / TI) * JSPLIT, 512, 0, stream>>>(adj, hT, e1, Bv, bv, accp, zp);
    k3_final<<<(BB * NN * CC / 4 + 255) / 256, 256, 0, stream>>>(accp, zp, out);
}

// Round 16
// 44.996 us; speedup vs baseline: 1.3162x; 1.0277x over previous
//
#include <hip/hip_runtime.h>
#include <cstdint>

#define BB 8
#define NN 2048
#define CC 64
#define TI 128           // i-rows per block (8 waves x 16)
#define JSPLIT 2
#define KRANGE (NN / JSPLIT)   // 1024 j per block
#define JCH 128                // adj reg-prefetch chunk
#define NCH (KRANGE / JCH)     // 8

typedef __attribute__((ext_vector_type(8))) _Float16 f16x8;
typedef __attribute__((ext_vector_type(2))) _Float16 f16x2;
typedef __attribute__((ext_vector_type(4))) float f32x4;
typedef __attribute__((ext_vector_type(4))) unsigned int u32x4;
typedef __attribute__((ext_vector_type(4))) int i32x4;

// ws layout (in floats):
static const size_t WS_H   = 0;                                  // B*N*C
static const size_t WS_E1  = WS_H  + (size_t)BB*NN*CC;           // B*N
static const size_t WS_BF  = WS_E1 + (size_t)BB*NN;              // B*N ushorts: f16 exp(e2)
static const size_t WS_bf  = WS_BF + (size_t)BB*NN/2;            // B*N ushorts: f16 exp(.01 e2)
static const size_t WS_HT  = WS_bf + (size_t)BB*NN/2;            // hT fp16: B*C*N ushorts
static const size_t WS_ACC = WS_HT + (size_t)BB*CC*NN/2;         // JSPLIT*B*N*C floats
static const size_t WS_Z   = WS_ACC + (size_t)JSPLIT*BB*NN*CC;   // JSPLIT*B*N

#define GL16(g, l) __builtin_amdgcn_global_load_lds( \
    (const __attribute__((address_space(1))) void*)(g), \
    (__attribute__((address_space(3))) void*)(uint32_t)(uintptr_t)(l), 16, 0, 0)
#define GL4(g, l) __builtin_amdgcn_global_load_lds( \
    (const __attribute__((address_space(1))) void*)(g), \
    (__attribute__((address_space(3))) void*)(uint32_t)(uintptr_t)(l), 4, 0, 0)
#define WAIT0()  asm volatile("s_waitcnt vmcnt(0)" ::: "memory")
#define BAR()    __builtin_amdgcn_s_barrier()

// ---------------- Kernel 1: h = inp @ W ; e1 ; Bf=f16(exp(e2)), bf=f16(exp(.01 e2)) ----------------
__global__ __launch_bounds__(256) void k1_proj(const float* __restrict__ inp,
        const float* __restrict__ Wm, const float* __restrict__ av,
        float* __restrict__ h, float* __restrict__ e1,
        unsigned short* __restrict__ Bf, unsigned short* __restrict__ bf) {
    __shared__ float inp_lds[256];
    int t = threadIdx.x;
    size_t base = (size_t)blockIdx.x * 256;
    inp_lds[t] = inp[base + t];
    __syncthreads();
    int r = t >> 6;
    int c = t & 63;
    const float* irow = &inp_lds[r * 64];
    float acc = 0.f;
    #pragma unroll
    for (int k = 0; k < 64; k++) acc = fmaf(irow[k], Wm[k * 64 + c], acc);
    size_t row = (size_t)blockIdx.x * 4 + r;
    h[row * 64 + c] = acc;
    float v1 = acc * av[c];
    float v2 = acc * av[64 + c];
    #pragma unroll
    for (int o = 32; o > 0; o >>= 1) {
        v1 += __shfl_down(v1, o);
        v2 += __shfl_down(v2, o);
    }
    if (c == 0) {
        e1[row] = v1;
        Bf[row] = __builtin_bit_cast(unsigned short, (_Float16)__expf(v2));
        bf[row] = __builtin_bit_cast(unsigned short, (_Float16)__expf(0.01f * v2));
    }
}

// ---------------- Kernel 1b: transpose h -> fp16 [b][c][n]; XCD-affine (b=bid&7) ----------------
__global__ __launch_bounds__(256) void k1b_transpose(const float* __restrict__ h,
        unsigned short* __restrict__ hT) {
    __shared__ float tile[64][65];
    int t = threadIdx.x;
    int b = blockIdx.x & 7;
    int i0 = ((blockIdx.x >> 3) & 31) * 64;
    const float* hb = h + ((size_t)b * NN + i0) * CC;
    #pragma unroll
    for (int q = 0; q < 16; q++) {
        int idx = q * 256 + t;
        tile[idx >> 6][idx & 63] = hb[idx];
    }
    __syncthreads();
    int c = t & 63;
    int rgrp = t >> 6;           // 4 groups of 16 rows
    unsigned int uh[8];
    #pragma unroll
    for (int p = 0; p < 8; p++) {
        unsigned int pack_h = 0;
        #pragma unroll
        for (int s = 0; s < 2; s++) {
            float v = tile[rgrp * 16 + p * 2 + s][c];
            _Float16 fh = (_Float16)v;
            unsigned int u = (unsigned int)__builtin_bit_cast(unsigned short, fh);
            pack_h |= u << (16 * s);
        }
        uh[p] = pack_h;
    }
    size_t off = ((size_t)b * 64 + c) * NN + i0 + rgrp * 16;   // in ushorts
    u32x4* dh = (u32x4*)(hT + off);
    dh[0] = u32x4{uh[0], uh[1], uh[2], uh[3]};
    dh[1] = u32x4{uh[4], uh[5], uh[6], uh[7]};
}

// ---------------- Kernel 2: fp16 MFMA attention; packed-f16 p-prep; h-half LDS-resident ----------------
// grid 256 @ 512 thr: b = bid&7 (XCD<->batch affinity). Structure = round-10 (best).
// p pair = pk_mul(pk_max(pk_mul(A2,B2), pk_mul(a2,b2)), mask2); mask2 bits = (a0|a1<<16)*0x3C00
// (adj in {0,1} -> exact f16 1.0/0.0). Zero transcendentals, zero cvt/pack in the loop.
__global__ __launch_bounds__(512, 1) void k2_mfma(const int* __restrict__ adj,
        const unsigned short* __restrict__ hT,
        const float* __restrict__ e1, const unsigned short* __restrict__ Bf,
        const unsigned short* __restrict__ bf,
        float* __restrict__ accp, float* __restrict__ zp) {
    __shared__ __align__(16) char smem[135168];   // 128 KB h + 2 KB Bf + 2 KB bf
    char* BL = smem + 131072;
    char* bL = smem + 133120;

    int bid = blockIdx.x;
    int b    = bid & 7;
    int rest = bid >> 3;
    int s    = rest & 1;
    int tile = rest >> 1;          // 0..15
    int i0 = tile * TI;
    int jbase = s * KRANGE;

    int t = threadIdx.x;
    int w = t >> 6;
    int l = t & 63;
    int col = l & 15;
    int kg  = l >> 4;              // k-group 0..3

    const int* adjrow = adj + ((size_t)b * NN + i0 + w * 16 + col) * NN + jbase;
    float e1v = e1[(size_t)b * NN + i0 + w * 16 + col];
    _Float16 Ah = (_Float16)__expf(e1v);
    _Float16 ah = (_Float16)__expf(0.01f * e1v);
    f16x2 A2 = {Ah, Ah};
    f16x2 a2 = {ah, ah};
    const unsigned short* Bfb = Bf + (size_t)b * NN;
    const unsigned short* bfb = bf + (size_t)b * NN;
    const unsigned short* hTb = hT + (size_t)b * 64 * NN;

    f32x4 acc[4];
    #pragma unroll
    for (int n = 0; n < 4; n++) acc[n] = f32x4{0.f, 0.f, 0.f, 0.f};
    f32x4 accZ = f32x4{0.f, 0.f, 0.f, 0.f};

    _Float16 onev = (_Float16)1.0f, zerov = (_Float16)0.0f;
    f16x8 onesf;
    #pragma unroll
    for (int i = 0; i < 8; i++) onesf[i] = (col == 0) ? onev : zerov;

    i32x4 aA[8], aB[8];

#define ADJP(jcN, arr) { \
    _Pragma("unroll") \
    for (int q = 0; q < 4; q++) { \
        const i32x4* ap = (const i32x4*)(adjrow + (jcN) * JCH + q * 32 + kg * 8); \
        arr[2 * q]     = ap[0]; \
        arr[2 * q + 1] = ap[1]; \
    } \
}

#define COMPUTE(jcN, arr) { \
    _Pragma("unroll") \
    for (int ks4 = 0; ks4 < 4; ks4++) { \
        int ks = (jcN) * 4 + ks4; \
        int krel2 = (ks * 32 + kg * 8) * 2; \
        i32x4 a0 = arr[2 * ks4]; \
        i32x4 a1 = arr[2 * ks4 + 1]; \
        u32x4 Bu = __builtin_bit_cast(u32x4, *(const f32x4*)(BL + krel2)); \
        u32x4 bu = __builtin_bit_cast(u32x4, *(const f32x4*)(bL + krel2)); \
        int ms[8] = {a0.x, a0.y, a0.z, a0.w, a1.x, a1.y, a1.z, a1.w}; \
        unsigned int Bw[4] = {Bu.x, Bu.y, Bu.z, Bu.w}; \
        unsigned int bw[4] = {bu.x, bu.y, bu.z, bu.w}; \
        unsigned int pfu[4]; \
        _Pragma("unroll") \
        for (int i = 0; i < 4; i++) { \
            f16x2 Bp = __builtin_bit_cast(f16x2, Bw[i]); \
            f16x2 bp = __builtin_bit_cast(f16x2, bw[i]); \
            f16x2 hi = A2 * Bp; \
            f16x2 lo = a2 * bp; \
            f16x2 mx = __builtin_elementwise_max(hi, lo); \
            unsigned int fm = ((unsigned int)ms[2 * i] | ((unsigned int)ms[2 * i + 1] << 16)) * 0x3C00u; \
            f16x2 pm = __builtin_bit_cast(f16x2, fm); \
            pfu[i] = __builtin_bit_cast(unsigned int, (f16x2)(mx * pm)); \
        } \
        f16x8 pf = __builtin_bit_cast(f16x8, u32x4{pfu[0], pfu[1], pfu[2], pfu[3]}); \
        int g = ks * 4 + kg; \
        _Pragma("unroll") \
        for (int n = 0; n < 4; n++) { \
            int c = n * 16 + col; \
            int p = (g & 120) | ((g ^ c) & 7); \
            f16x8 hv = __builtin_bit_cast(f16x8, *(const f32x4*)(smem + c * 2048 + p * 16)); \
            acc[n] = __builtin_amdgcn_mfma_f32_16x16x32_f16(pf, hv, acc[n], 0, 0, 0); \
        } \
        accZ = __builtin_amdgcn_mfma_f32_16x16x32_f16(pf, onesf, accZ, 0, 0, 0); \
    } \
}

    // ---- adj chunk 0 prefetch first: latency overlaps the h staging ----
    ADJP(0, aA);

    // ---- stage h-half (128 KB) once: 16 GL16 per wave, swizzled global source ----
    #pragma unroll
    for (int it = 0; it < 16; it++) {
        int k16 = it * 8 + w;            // half-row index 0..127 (wave-uniform)
        int c   = k16 >> 1;              // LDS row
        int p   = (k16 & 1) * 64 + l;    // physical granule within row
        int g   = (p & 120) | ((p ^ c) & 7);   // logical granule (involution)
        const unsigned short* src = hTb + (size_t)c * NN + jbase + g * 8;
        GL16(src, smem + (size_t)k16 * 1024);
    }
    // ---- stage Bf/bf half-slices (2 KB each) once: 1 GL4 per wave per array ----
    GL4(Bfb + jbase + w * 128 + l * 2, BL + w * 256);
    GL4(bfb + jbase + w * 128 + l * 2, bL + w * 256);
    WAIT0();
    BAR();

    // ---- barrier-free main loop, 2-deep rotation (round-10 proven pattern) ----
    #pragma unroll
    for (int jc = 0; jc < NCH; jc += 2) {
        ADJP(jc + 1, aB);
        COMPUTE(jc, aA);
        if (jc + 2 < NCH) ADJP(jc + 2, aA);
        COMPUTE(jc + 1, aB);
    }

    // ---- epilogue: partial acc/Z to ws (C/D layout: col=lane&15, row=kg*4+reg) ----
    size_t orow = (size_t)s * BB * NN + (size_t)b * NN + i0 + w * 16 + kg * 4;
    float* accout = accp + orow * CC;
    #pragma unroll
    for (int n = 0; n < 4; n++) {
        #pragma unroll
        for (int r = 0; r < 4; r++) {
            accout[(size_t)r * CC + n * 16 + col] = acc[n][r];
        }
    }
    if (col == 0) {
        #pragma unroll
        for (int r = 0; r < 4; r++) zp[orow + r] = accZ[r];
    }
#undef ADJP
#undef COMPUTE
}

// ---------------- Kernel 3: out = sum_s acc[s] / sum_s z[s] ----------------
__global__ __launch_bounds__(256) void k3_final(const float* __restrict__ accp,
        const float* __restrict__ zp, float* __restrict__ out) {
    int idx = blockIdx.x * 256 + threadIdx.x;      // float4 index
    const int TOT4 = BB * NN * CC / 4;             // 262144
    if (idx >= TOT4) return;
    int row = idx >> 4;
    f32x4 s0 = ((const f32x4*)accp)[idx];
    f32x4 s1 = ((const f32x4*)accp)[idx + TOT4];
    float z = zp[row] + zp[row + BB * NN];
    float inv = (z > 0.f) ? (1.0f / z) : 0.f;
    f32x4 o;
    o.x = (s0.x + s1.x) * inv;
    o.y = (s0.y + s1.y) * inv;
    o.z = (s0.z + s1.z) * inv;
    o.w = (s0.w + s1.w) * inv;
    ((f32x4*)out)[idx] = o;
}

extern "C" void kernel_launch(void* const* d_in, const int* in_sizes, int n_in,
                              void* d_out, int out_size, void* d_ws, size_t ws_size,
                              hipStream_t stream) {
    const float* inp = (const float*)d_in[0];
    const int*   adj = (const int*)d_in[1];
    const float* Wm  = (const float*)d_in[2];
    const float* av  = (const float*)d_in[3];
    float* ws = (float*)d_ws;
    float* h    = ws + WS_H;
    float* e1   = ws + WS_E1;
    unsigned short* Bf = (unsigned short*)(ws + WS_BF);
    unsigned short* bf = (unsigned short*)(ws + WS_bf);
    unsigned short* hT = (unsigned short*)(ws + WS_HT);
    float* accp = ws + WS_ACC;
    float* zp   = ws + WS_Z;
    float* out  = (float*)d_out;

    k1_proj<<<BB * NN / 4, 256, 0, stream>>>(inp, Wm, av, h, e1, Bf, bf);
    k1b_transpose<<<BB * (NN / 64), 256, 0, stream>>>(h, hT);
    k2_mfma<<<BB * (NN / TI) * JSPLIT, 512, 0, stream>>>(adj, hT, e1, Bf, bf, accp, zp);
    k3_final<<<(BB * NN * CC / 4 + 255) / 256, 256, 0, stream>>>(accp, zp, out);
}